// Round 4
// baseline (994.347 us; speedup 1.0000x reference)
//
#include <hip/hip_runtime.h>
#include <hip/hip_bf16.h>
#include <math.h>

#define N_NODES 100000
#define N_EDGES 800000

// ================= degree / CSR build =================
__global__ void k_zero_deg(int* __restrict__ deg) {
    int i = blockIdx.x * blockDim.x + threadIdx.x;
    if (i < N_NODES) deg[i] = 0;
}

__global__ void k_hist(const int* __restrict__ edst, int* __restrict__ deg) {
    int e = blockIdx.x * blockDim.x + threadIdx.x;
    if (e < N_EDGES) atomicAdd(&deg[edst[e]], 1);
}

__global__ void k_dinv(const int* __restrict__ deg, float* __restrict__ dinv) {
    int i = blockIdx.x * blockDim.x + threadIdx.x;
    if (i < N_NODES) dinv[i] = rsqrtf((float)(deg[i] + 1));   // +1 self-loop
}

// exclusive scan, 256/block
__global__ void k_scan1(const int* __restrict__ deg, int* __restrict__ off,
                        int* __restrict__ bsum, int n) {
    __shared__ int s[256];
    int t = threadIdx.x;
    int i = blockIdx.x * 256 + t;
    int v = (i < n) ? deg[i] : 0;
    s[t] = v;
    __syncthreads();
    #pragma unroll
    for (int d = 1; d < 256; d <<= 1) {
        int x = (t >= d) ? s[t - d] : 0;
        __syncthreads();
        s[t] += x;
        __syncthreads();
    }
    if (i < n) off[i] = s[t] - v;            // exclusive within block
    if (t == 255) bsum[blockIdx.x] = s[255];
}

__global__ void k_scan2(int* __restrict__ bsum, int nb) {
    __shared__ int s[512];
    int t = threadIdx.x;
    int v = (t < nb) ? bsum[t] : 0;
    s[t] = v;
    __syncthreads();
    #pragma unroll
    for (int d = 1; d < 512; d <<= 1) {
        int x = (t >= d) ? s[t - d] : 0;
        __syncthreads();
        s[t] += x;
        __syncthreads();
    }
    if (t < nb) bsum[t] = s[t] - v;          // exclusive block offsets
}

__global__ void k_scan3(int* __restrict__ off, const int* __restrict__ bsum,
                        int* __restrict__ cur, int n) {
    int i = blockIdx.x * blockDim.x + threadIdx.x;
    if (i < n) {
        int o = off[i] + bsum[i >> 8];
        off[i] = o;
        cur[i] = o;
    }
    if (i == n) off[n] = N_EDGES;
}

__global__ void k_scatter(const int* __restrict__ esrc, const int* __restrict__ edst,
                          const float* __restrict__ dinv,
                          int* __restrict__ cur, int* __restrict__ csr_src,
                          float* __restrict__ csr_w) {
    int e = blockIdx.x * blockDim.x + threadIdx.x;
    if (e >= N_EDGES) return;
    int s = esrc[e], d = edst[e];
    int pos = atomicAdd(&cur[d], 1);
    csr_src[pos] = s;
    csr_w[pos] = dinv[s] * dinv[d];
}

// ================= node GEMM: raw = (relu?)in[N,128] @ W[128,128] =================
// In-place safe (raw==in): each block stages its own rows to LDS before writing.
template<bool RELU>
__global__ __launch_bounds__(256) void k_node_gemm(
    const float* __restrict__ in, const float* __restrict__ W,
    float* __restrict__ raw, int nrows)
{
    __shared__ float sIn[64][132];
    __shared__ float sW[64][128];
    const int t = threadIdx.x;
    const int row0 = blockIdx.x * 64;

    #pragma unroll
    for (int i = 0; i < 8; ++i) {
        int li = t + 256 * i;
        int r = li >> 5, c4 = li & 31;
        float4 v = make_float4(0.f, 0.f, 0.f, 0.f);
        if (row0 + r < nrows) v = ((const float4*)in)[(size_t)(row0 + r) * 32 + c4];
        if (RELU) {
            v.x = fmaxf(v.x, 0.f); v.y = fmaxf(v.y, 0.f);
            v.z = fmaxf(v.z, 0.f); v.w = fmaxf(v.w, 0.f);
        }
        *(float4*)&sIn[r][c4 << 2] = v;
    }

    const int ty = t >> 4, tx = t & 15;
    const int r0 = ty << 2, c0 = tx << 3;
    float acc[4][8];
    #pragma unroll
    for (int i = 0; i < 4; ++i)
        #pragma unroll
        for (int j = 0; j < 8; ++j) acc[i][j] = 0.f;

    for (int kc = 0; kc < 2; ++kc) {
        if (kc) __syncthreads();
        #pragma unroll
        for (int i = 0; i < 8; ++i) {
            int li = t + 256 * i;
            int kk = li >> 5, c4 = li & 31;
            *(float4*)&sW[kk][c4 << 2] = ((const float4*)W)[(size_t)(kc * 64 + kk) * 32 + c4];
        }
        __syncthreads();
        #pragma unroll 4
        for (int k4 = 0; k4 < 16; ++k4) {
            float4 a[4];
            #pragma unroll
            for (int i = 0; i < 4; ++i) a[i] = *(const float4*)&sIn[r0 + i][kc * 64 + (k4 << 2)];
            #pragma unroll
            for (int kk = 0; kk < 4; ++kk) {
                float4 w0 = *(const float4*)&sW[(k4 << 2) + kk][c0];
                float4 w1 = *(const float4*)&sW[(k4 << 2) + kk][c0 + 4];
                #pragma unroll
                for (int i = 0; i < 4; ++i) {
                    float av = (kk == 0) ? a[i].x : (kk == 1) ? a[i].y : (kk == 2) ? a[i].z : a[i].w;
                    acc[i][0] += av * w0.x; acc[i][1] += av * w0.y;
                    acc[i][2] += av * w0.z; acc[i][3] += av * w0.w;
                    acc[i][4] += av * w1.x; acc[i][5] += av * w1.y;
                    acc[i][6] += av * w1.z; acc[i][7] += av * w1.w;
                }
            }
        }
    }

    #pragma unroll
    for (int i = 0; i < 4; ++i) {
        int gr = row0 + r0 + i;
        if (gr < nrows) {
            *(float4*)&raw[(size_t)gr * 128 + c0] =
                make_float4(acc[i][0], acc[i][1], acc[i][2], acc[i][3]);
            *(float4*)&raw[(size_t)gr * 128 + c0 + 4] =
                make_float4(acc[i][4], acc[i][5], acc[i][6], acc[i][7]);
        }
    }
}

// ================= fused P/Q GEMM =================
// P = relu(in) @ Wm1[0:128]   ;  Q = relu(in) @ Wm1[128:256]
// Stages relu(in) tile ONCE for both products. In-place safe for Q==in.
__global__ __launch_bounds__(256) void k_node_gemm_pq(
    const float* __restrict__ in, const float* __restrict__ Wm1,
    float* __restrict__ P, float* __restrict__ Q, int nrows)
{
    __shared__ float sIn[64][132];
    __shared__ float sW[64][128];
    const int t = threadIdx.x;
    const int row0 = blockIdx.x * 64;

    #pragma unroll
    for (int i = 0; i < 8; ++i) {
        int li = t + 256 * i;
        int r = li >> 5, c4 = li & 31;
        float4 v = make_float4(0.f, 0.f, 0.f, 0.f);
        if (row0 + r < nrows) v = ((const float4*)in)[(size_t)(row0 + r) * 32 + c4];
        v.x = fmaxf(v.x, 0.f); v.y = fmaxf(v.y, 0.f);
        v.z = fmaxf(v.z, 0.f); v.w = fmaxf(v.w, 0.f);
        *(float4*)&sIn[r][c4 << 2] = v;
    }

    const int ty = t >> 4, tx = t & 15;
    const int r0 = ty << 2, c0 = tx << 3;

    bool first = true;
    for (int half = 0; half < 2; ++half) {
        float acc[4][8];
        #pragma unroll
        for (int i = 0; i < 4; ++i)
            #pragma unroll
            for (int j = 0; j < 8; ++j) acc[i][j] = 0.f;

        for (int kc = 0; kc < 2; ++kc) {
            if (!first) __syncthreads();   // all reads of old sW done
            first = false;
            #pragma unroll
            for (int i = 0; i < 8; ++i) {
                int li = t + 256 * i;
                int kk = li >> 5, c4 = li & 31;
                *(float4*)&sW[kk][c4 << 2] =
                    ((const float4*)Wm1)[(size_t)(half * 128 + kc * 64 + kk) * 32 + c4];
            }
            __syncthreads();               // covers sIn (first iter) + sW
            #pragma unroll 4
            for (int k4 = 0; k4 < 16; ++k4) {
                float4 a[4];
                #pragma unroll
                for (int i = 0; i < 4; ++i) a[i] = *(const float4*)&sIn[r0 + i][kc * 64 + (k4 << 2)];
                #pragma unroll
                for (int kk = 0; kk < 4; ++kk) {
                    float4 w0 = *(const float4*)&sW[(k4 << 2) + kk][c0];
                    float4 w1 = *(const float4*)&sW[(k4 << 2) + kk][c0 + 4];
                    #pragma unroll
                    for (int i = 0; i < 4; ++i) {
                        float av = (kk == 0) ? a[i].x : (kk == 1) ? a[i].y : (kk == 2) ? a[i].z : a[i].w;
                        acc[i][0] += av * w0.x; acc[i][1] += av * w0.y;
                        acc[i][2] += av * w0.z; acc[i][3] += av * w0.w;
                        acc[i][4] += av * w1.x; acc[i][5] += av * w1.y;
                        acc[i][6] += av * w1.z; acc[i][7] += av * w1.w;
                    }
                }
            }
        }

        float* outp = half ? Q : P;
        #pragma unroll
        for (int i = 0; i < 4; ++i) {
            int gr = row0 + r0 + i;
            if (gr < nrows) {
                *(float4*)&outp[(size_t)gr * 128 + c0] =
                    make_float4(acc[i][0], acc[i][1], acc[i][2], acc[i][3]);
                *(float4*)&outp[(size_t)gr * 128 + c0 + 4] =
                    make_float4(acc[i][4], acc[i][5], acc[i][6], acc[i][7]);
            }
        }
    }
}

// ================= CSR aggregation =================
// out[i][:] = bias[:] + dinv[i]^2 * raw[i][:] + sum_{e: dst=i} w_e * raw[src_e][:]
__global__ __launch_bounds__(256) void k_agg_csr(
    const float* __restrict__ raw, const float* __restrict__ dinv,
    const int* __restrict__ off, const int* __restrict__ csr_src,
    const float* __restrict__ csr_w, const float* __restrict__ bias,
    float* __restrict__ outp)
{
    const int t = threadIdx.x;
    const int node = blockIdx.x * 8 + (t >> 5);
    const int lane = t & 31;
    if (node >= N_NODES) return;

    float di = dinv[node];
    float w0 = di * di;
    float4 acc = ((const float4*)bias)[lane];
    float4 v = ((const float4*)raw)[(size_t)node * 32 + lane];
    acc.x += w0 * v.x; acc.y += w0 * v.y; acc.z += w0 * v.z; acc.w += w0 * v.w;

    int beg = off[node], end = off[node + 1];
    for (int j = beg; j < end; ++j) {
        int s = csr_src[j];
        float w = csr_w[j];
        float4 u = ((const float4*)raw)[(size_t)s * 32 + lane];
        acc.x += w * u.x; acc.y += w * u.y; acc.z += w * u.z; acc.w += w * u.w;
    }
    ((float4*)outp)[(size_t)node * 32 + lane] = acc;
}

// ================= fused edge MLP =================
// z1 = relu(P[src] + Q[dst] + bm1); z2 = relu(z1 @ Wm2 + bm2); out = sigmoid(z2 @ Wm3 + bm3)
__global__ __launch_bounds__(256) void k_edge_mlp(
    const int* __restrict__ esrc, const int* __restrict__ edst,
    const float* __restrict__ P, const float* __restrict__ Q,
    const float* __restrict__ bm1,
    const float* __restrict__ Wm2, const float* __restrict__ bm2,
    const float* __restrict__ Wm3, const float* __restrict__ bm3,
    float* __restrict__ outp)
{
    __shared__ float sZ[64][132];
    __shared__ float sW[64][128];
    __shared__ int sIdx[2][64];

    const int t = threadIdx.x;
    const int e0 = blockIdx.x * 64;

    if (t < 64) sIdx[0][t] = esrc[e0 + t];
    else if (t < 128) sIdx[1][t - 64] = edst[e0 + t - 64];
    __syncthreads();

    #pragma unroll
    for (int i = 0; i < 8; ++i) {
        int li = t + 256 * i;
        int e = li >> 5, c4 = li & 31;
        int s = sIdx[0][e], d = sIdx[1][e];
        float4 p = ((const float4*)P)[(size_t)s * 32 + c4];
        float4 q = ((const float4*)Q)[(size_t)d * 32 + c4];
        float4 bb = ((const float4*)bm1)[c4];
        *(float4*)&sZ[e][c4 << 2] = make_float4(
            fmaxf(p.x + q.x + bb.x, 0.f), fmaxf(p.y + q.y + bb.y, 0.f),
            fmaxf(p.z + q.z + bb.z, 0.f), fmaxf(p.w + q.w + bb.w, 0.f));
    }

    const int ty = t >> 4, tx = t & 15;
    const int r0 = ty << 2, c0 = tx << 3;

    float acc[4][8];
    {
        float4 bb0 = ((const float4*)bm2)[c0 >> 2];
        float4 bb1 = ((const float4*)bm2)[(c0 >> 2) + 1];
        #pragma unroll
        for (int i = 0; i < 4; ++i) {
            acc[i][0] = bb0.x; acc[i][1] = bb0.y; acc[i][2] = bb0.z; acc[i][3] = bb0.w;
            acc[i][4] = bb1.x; acc[i][5] = bb1.y; acc[i][6] = bb1.z; acc[i][7] = bb1.w;
        }
    }

    for (int kc = 0; kc < 2; ++kc) {
        if (kc) __syncthreads();
        #pragma unroll
        for (int i = 0; i < 8; ++i) {
            int li = t + 256 * i;
            int kk = li >> 5, c4 = li & 31;
            *(float4*)&sW[kk][c4 << 2] = ((const float4*)Wm2)[(size_t)(kc * 64 + kk) * 32 + c4];
        }
        __syncthreads();
        #pragma unroll 4
        for (int k4 = 0; k4 < 16; ++k4) {
            float4 a[4];
            #pragma unroll
            for (int i = 0; i < 4; ++i) a[i] = *(const float4*)&sZ[r0 + i][kc * 64 + (k4 << 2)];
            #pragma unroll
            for (int kk = 0; kk < 4; ++kk) {
                float4 w0 = *(const float4*)&sW[(k4 << 2) + kk][c0];
                float4 w1 = *(const float4*)&sW[(k4 << 2) + kk][c0 + 4];
                #pragma unroll
                for (int i = 0; i < 4; ++i) {
                    float av = (kk == 0) ? a[i].x : (kk == 1) ? a[i].y : (kk == 2) ? a[i].z : a[i].w;
                    acc[i][0] += av * w0.x; acc[i][1] += av * w0.y;
                    acc[i][2] += av * w0.z; acc[i][3] += av * w0.w;
                    acc[i][4] += av * w1.x; acc[i][5] += av * w1.y;
                    acc[i][6] += av * w1.z; acc[i][7] += av * w1.w;
                }
            }
        }
    }

    float w3[8];
    #pragma unroll
    for (int j = 0; j < 8; ++j) w3[j] = Wm3[c0 + j];
    float b3 = bm3[0];
    #pragma unroll
    for (int i = 0; i < 4; ++i) {
        float p = 0.f;
        #pragma unroll
        for (int j = 0; j < 8; ++j) p += fmaxf(acc[i][j], 0.f) * w3[j];
        p += __shfl_xor(p, 1);
        p += __shfl_xor(p, 2);
        p += __shfl_xor(p, 4);
        p += __shfl_xor(p, 8);
        if (tx == 0) {
            float v = p + b3;
            outp[e0 + r0 + i] = 1.f / (1.f + expf(-v));
        }
    }
}

// ================= launch =================
extern "C" void kernel_launch(void* const* d_in, const int* in_sizes, int n_in,
                              void* d_out, int out_size, void* d_ws, size_t ws_size,
                              hipStream_t stream) {
    const float* x   = (const float*)d_in[0];
    const int*   ei  = (const int*)d_in[1];
    const float* W1  = (const float*)d_in[2];
    const float* b1  = (const float*)d_in[3];
    const float* W2  = (const float*)d_in[4];
    const float* b2  = (const float*)d_in[5];
    const float* Wm1 = (const float*)d_in[6];
    const float* bm1 = (const float*)d_in[7];
    const float* Wm2 = (const float*)d_in[8];
    const float* bm2 = (const float*)d_in[9];
    const float* Wm3 = (const float*)d_in[10];
    const float* bm3 = (const float*)d_in[11];
    const int* esrc = ei;
    const int* edst = ei + N_EDGES;
    float* outp = (float*)d_out;

    // workspace layout
    float* ws = (float*)d_ws;
    float* dinv = ws;                                   // 100096 floats
    float* A = ws + 100096;                             // N*128
    float* B = A + (size_t)N_NODES * 128;               // N*128
    int* deg     = (int*)(B + (size_t)N_NODES * 128);   // N
    int* off     = deg + N_NODES;                       // N+1
    int* cur     = off + N_NODES + 1;                   // N
    int* bsum    = cur + N_NODES;                       // 512
    int* csr_src = bsum + 512;                          // E
    float* csr_w = (float*)(csr_src + N_EDGES);         // E

    const int nb = (N_NODES + 255) / 256;               // 391 scan blocks

    // ---- CSR build ----
    k_zero_deg<<<nb, 256, 0, stream>>>(deg);
    k_hist<<<(N_EDGES + 255) / 256, 256, 0, stream>>>(edst, deg);
    k_dinv<<<nb, 256, 0, stream>>>(deg, dinv);
    k_scan1<<<nb, 256, 0, stream>>>(deg, off, bsum, N_NODES);
    k_scan2<<<1, 512, 0, stream>>>(bsum, nb);
    k_scan3<<<(N_NODES + 256) / 256, 256, 0, stream>>>(off, bsum, cur, N_NODES);
    k_scatter<<<(N_EDGES + 255) / 256, 256, 0, stream>>>(esrc, edst, dinv, cur, csr_src, csr_w);

    const int gemm_blocks = (N_NODES + 63) / 64;
    const int agg_blocks = (N_NODES + 7) / 8;

    // ---- layer 1: A = x @ W1 ; B = b1 + norm-agg(A) ----
    k_node_gemm<false><<<gemm_blocks, 256, 0, stream>>>(x, W1, A, N_NODES);
    k_agg_csr<<<agg_blocks, 256, 0, stream>>>(A, dinv, off, csr_src, csr_w, b1, B);

    // ---- layer 2: A = relu(B) @ W2 ; B = b2 + norm-agg(A) ----
    k_node_gemm<true><<<gemm_blocks, 256, 0, stream>>>(B, W2, A, N_NODES);
    k_agg_csr<<<agg_blocks, 256, 0, stream>>>(A, dinv, off, csr_src, csr_w, b2, B);

    // ---- edge-MLP layer-1 decomposition (fused): P -> A, Q -> B (in-place safe) ----
    k_node_gemm_pq<<<gemm_blocks, 256, 0, stream>>>(B, Wm1, A, B, N_NODES);

    // ---- fused edge MLP ----
    k_edge_mlp<<<N_EDGES / 64, 256, 0, stream>>>(esrc, edst, A, B, bm1, Wm2, bm2,
                                                 Wm3, bm3, outp);
}

// Round 5
// 767.272 us; speedup vs baseline: 1.2960x; 1.2960x over previous
//
#include <hip/hip_runtime.h>
#include <hip/hip_bf16.h>
#include <math.h>

#define N_NODES 100000
#define N_EDGES 800000

typedef float f32x4 __attribute__((ext_vector_type(4)));
typedef short bf16x8 __attribute__((ext_vector_type(8)));

__device__ inline unsigned short bf16_of(float f) {
    union { __hip_bfloat16 b; unsigned short u; } cv;
    cv.b = __float2bfloat16(f);
    return cv.u;
}
__device__ inline float f32_of(unsigned short u) {
    union { __hip_bfloat16 b; unsigned short u; } cv;
    cv.u = u;
    return __bfloat162float(cv.b);
}

// ================= degree / CSR build =================
__global__ void k_zero_deg(int* __restrict__ deg) {
    int i = blockIdx.x * blockDim.x + threadIdx.x;
    if (i < N_NODES) deg[i] = 0;
}

__global__ void k_hist(const int* __restrict__ edst, int* __restrict__ deg) {
    int e = blockIdx.x * blockDim.x + threadIdx.x;
    if (e < N_EDGES) atomicAdd(&deg[edst[e]], 1);
}

__global__ void k_dinv(const int* __restrict__ deg, float* __restrict__ dinv) {
    int i = blockIdx.x * blockDim.x + threadIdx.x;
    if (i < N_NODES) dinv[i] = rsqrtf((float)(deg[i] + 1));   // +1 self-loop
}

// exclusive scan, 256/block
__global__ void k_scan1(const int* __restrict__ deg, int* __restrict__ off,
                        int* __restrict__ bsum, int n) {
    __shared__ int s[256];
    int t = threadIdx.x;
    int i = blockIdx.x * 256 + t;
    int v = (i < n) ? deg[i] : 0;
    s[t] = v;
    __syncthreads();
    #pragma unroll
    for (int d = 1; d < 256; d <<= 1) {
        int x = (t >= d) ? s[t - d] : 0;
        __syncthreads();
        s[t] += x;
        __syncthreads();
    }
    if (i < n) off[i] = s[t] - v;            // exclusive within block
    if (t == 255) bsum[blockIdx.x] = s[255];
}

__global__ void k_scan2(int* __restrict__ bsum, int nb) {
    __shared__ int s[512];
    int t = threadIdx.x;
    int v = (t < nb) ? bsum[t] : 0;
    s[t] = v;
    __syncthreads();
    #pragma unroll
    for (int d = 1; d < 512; d <<= 1) {
        int x = (t >= d) ? s[t - d] : 0;
        __syncthreads();
        s[t] += x;
        __syncthreads();
    }
    if (t < nb) bsum[t] = s[t] - v;          // exclusive block offsets
}

__global__ void k_scan3(int* __restrict__ off, const int* __restrict__ bsum,
                        int* __restrict__ cur, int n) {
    int i = blockIdx.x * blockDim.x + threadIdx.x;
    if (i < n) {
        int o = off[i] + bsum[i >> 8];
        off[i] = o;
        cur[i] = o;
    }
    if (i == n) off[n] = N_EDGES;
}

__global__ void k_scatter(const int* __restrict__ esrc, const int* __restrict__ edst,
                          const float* __restrict__ dinv,
                          int* __restrict__ cur, int* __restrict__ csr_src,
                          float* __restrict__ csr_w) {
    int e = blockIdx.x * blockDim.x + threadIdx.x;
    if (e >= N_EDGES) return;
    int s = esrc[e], d = edst[e];
    int pos = atomicAdd(&cur[d], 1);
    csr_src[pos] = s;
    csr_w[pos] = dinv[s] * dinv[d];
}

// ================= Wm2 bf16 hi/lo split into MFMA fragment layout =================
// frag index for (k, c): lane = ((k>>3)&3)*16 + (c&15), elem = k&7, tile = (k>>5)*8 + (c>>4)
__global__ void k_split_w(const float* __restrict__ Wm2, unsigned short* __restrict__ Wh,
                          unsigned short* __restrict__ Wl) {
    int idx = blockIdx.x * 256 + threadIdx.x;
    if (idx >= 128 * 128) return;
    int k = idx >> 7, c = idx & 127;
    float wv = Wm2[idx];
    unsigned short h = bf16_of(wv);
    unsigned short lo = bf16_of(wv - f32_of(h));
    int fi = (((k >> 5) * 8 + (c >> 4)) * 64 + (((k >> 3) & 3) * 16 + (c & 15))) * 8 + (k & 7);
    Wh[fi] = h;
    Wl[fi] = lo;
}

// ================= node GEMM: raw = (relu?)in[N,128] @ W[128,128] =================
// In-place safe (raw==in): each block stages its own rows to LDS before writing.
template<bool RELU>
__global__ __launch_bounds__(256) void k_node_gemm(
    const float* __restrict__ in, const float* __restrict__ W,
    float* __restrict__ raw, int nrows)
{
    __shared__ float sIn[64][132];
    __shared__ float sW[64][128];
    const int t = threadIdx.x;
    const int row0 = blockIdx.x * 64;

    #pragma unroll
    for (int i = 0; i < 8; ++i) {
        int li = t + 256 * i;
        int r = li >> 5, c4 = li & 31;
        float4 v = make_float4(0.f, 0.f, 0.f, 0.f);
        if (row0 + r < nrows) v = ((const float4*)in)[(size_t)(row0 + r) * 32 + c4];
        if (RELU) {
            v.x = fmaxf(v.x, 0.f); v.y = fmaxf(v.y, 0.f);
            v.z = fmaxf(v.z, 0.f); v.w = fmaxf(v.w, 0.f);
        }
        *(float4*)&sIn[r][c4 << 2] = v;
    }

    const int ty = t >> 4, tx = t & 15;
    const int r0 = ty << 2, c0 = tx << 3;
    float acc[4][8];
    #pragma unroll
    for (int i = 0; i < 4; ++i)
        #pragma unroll
        for (int j = 0; j < 8; ++j) acc[i][j] = 0.f;

    for (int kc = 0; kc < 2; ++kc) {
        if (kc) __syncthreads();
        #pragma unroll
        for (int i = 0; i < 8; ++i) {
            int li = t + 256 * i;
            int kk = li >> 5, c4 = li & 31;
            *(float4*)&sW[kk][c4 << 2] = ((const float4*)W)[(size_t)(kc * 64 + kk) * 32 + c4];
        }
        __syncthreads();
        #pragma unroll 4
        for (int k4 = 0; k4 < 16; ++k4) {
            float4 a[4];
            #pragma unroll
            for (int i = 0; i < 4; ++i) a[i] = *(const float4*)&sIn[r0 + i][kc * 64 + (k4 << 2)];
            #pragma unroll
            for (int kk = 0; kk < 4; ++kk) {
                float4 w0 = *(const float4*)&sW[(k4 << 2) + kk][c0];
                float4 w1 = *(const float4*)&sW[(k4 << 2) + kk][c0 + 4];
                #pragma unroll
                for (int i = 0; i < 4; ++i) {
                    float av = (kk == 0) ? a[i].x : (kk == 1) ? a[i].y : (kk == 2) ? a[i].z : a[i].w;
                    acc[i][0] += av * w0.x; acc[i][1] += av * w0.y;
                    acc[i][2] += av * w0.z; acc[i][3] += av * w0.w;
                    acc[i][4] += av * w1.x; acc[i][5] += av * w1.y;
                    acc[i][6] += av * w1.z; acc[i][7] += av * w1.w;
                }
            }
        }
    }

    #pragma unroll
    for (int i = 0; i < 4; ++i) {
        int gr = row0 + r0 + i;
        if (gr < nrows) {
            *(float4*)&raw[(size_t)gr * 128 + c0] =
                make_float4(acc[i][0], acc[i][1], acc[i][2], acc[i][3]);
            *(float4*)&raw[(size_t)gr * 128 + c0 + 4] =
                make_float4(acc[i][4], acc[i][5], acc[i][6], acc[i][7]);
        }
    }
}

// ================= fused P/Q GEMM =================
// P = relu(in) @ Wm1[0:128]   ;  Q = relu(in) @ Wm1[128:256]
__global__ __launch_bounds__(256) void k_node_gemm_pq(
    const float* __restrict__ in, const float* __restrict__ Wm1,
    float* __restrict__ P, float* __restrict__ Q, int nrows)
{
    __shared__ float sIn[64][132];
    __shared__ float sW[64][128];
    const int t = threadIdx.x;
    const int row0 = blockIdx.x * 64;

    #pragma unroll
    for (int i = 0; i < 8; ++i) {
        int li = t + 256 * i;
        int r = li >> 5, c4 = li & 31;
        float4 v = make_float4(0.f, 0.f, 0.f, 0.f);
        if (row0 + r < nrows) v = ((const float4*)in)[(size_t)(row0 + r) * 32 + c4];
        v.x = fmaxf(v.x, 0.f); v.y = fmaxf(v.y, 0.f);
        v.z = fmaxf(v.z, 0.f); v.w = fmaxf(v.w, 0.f);
        *(float4*)&sIn[r][c4 << 2] = v;
    }

    const int ty = t >> 4, tx = t & 15;
    const int r0 = ty << 2, c0 = tx << 3;

    bool first = true;
    for (int half = 0; half < 2; ++half) {
        float acc[4][8];
        #pragma unroll
        for (int i = 0; i < 4; ++i)
            #pragma unroll
            for (int j = 0; j < 8; ++j) acc[i][j] = 0.f;

        for (int kc = 0; kc < 2; ++kc) {
            if (!first) __syncthreads();
            first = false;
            #pragma unroll
            for (int i = 0; i < 8; ++i) {
                int li = t + 256 * i;
                int kk = li >> 5, c4 = li & 31;
                *(float4*)&sW[kk][c4 << 2] =
                    ((const float4*)Wm1)[(size_t)(half * 128 + kc * 64 + kk) * 32 + c4];
            }
            __syncthreads();
            #pragma unroll 4
            for (int k4 = 0; k4 < 16; ++k4) {
                float4 a[4];
                #pragma unroll
                for (int i = 0; i < 4; ++i) a[i] = *(const float4*)&sIn[r0 + i][kc * 64 + (k4 << 2)];
                #pragma unroll
                for (int kk = 0; kk < 4; ++kk) {
                    float4 w0 = *(const float4*)&sW[(k4 << 2) + kk][c0];
                    float4 w1 = *(const float4*)&sW[(k4 << 2) + kk][c0 + 4];
                    #pragma unroll
                    for (int i = 0; i < 4; ++i) {
                        float av = (kk == 0) ? a[i].x : (kk == 1) ? a[i].y : (kk == 2) ? a[i].z : a[i].w;
                        acc[i][0] += av * w0.x; acc[i][1] += av * w0.y;
                        acc[i][2] += av * w0.z; acc[i][3] += av * w0.w;
                        acc[i][4] += av * w1.x; acc[i][5] += av * w1.y;
                        acc[i][6] += av * w1.z; acc[i][7] += av * w1.w;
                    }
                }
            }
        }

        float* outp = half ? Q : P;
        #pragma unroll
        for (int i = 0; i < 4; ++i) {
            int gr = row0 + r0 + i;
            if (gr < nrows) {
                *(float4*)&outp[(size_t)gr * 128 + c0] =
                    make_float4(acc[i][0], acc[i][1], acc[i][2], acc[i][3]);
                *(float4*)&outp[(size_t)gr * 128 + c0 + 4] =
                    make_float4(acc[i][4], acc[i][5], acc[i][6], acc[i][7]);
            }
        }
    }
}

// ================= CSR aggregation =================
__global__ __launch_bounds__(256) void k_agg_csr(
    const float* __restrict__ raw, const float* __restrict__ dinv,
    const int* __restrict__ off, const int* __restrict__ csr_src,
    const float* __restrict__ csr_w, const float* __restrict__ bias,
    float* __restrict__ outp)
{
    const int t = threadIdx.x;
    const int node = blockIdx.x * 8 + (t >> 5);
    const int lane = t & 31;
    if (node >= N_NODES) return;

    float di = dinv[node];
    float w0 = di * di;
    float4 acc = ((const float4*)bias)[lane];
    float4 v = ((const float4*)raw)[(size_t)node * 32 + lane];
    acc.x += w0 * v.x; acc.y += w0 * v.y; acc.z += w0 * v.z; acc.w += w0 * v.w;

    int beg = off[node], end = off[node + 1];
    for (int j = beg; j < end; ++j) {
        int s = csr_src[j];
        float w = csr_w[j];
        float4 u = ((const float4*)raw)[(size_t)s * 32 + lane];
        acc.x += w * u.x; acc.y += w * u.y; acc.z += w * u.z; acc.w += w * u.w;
    }
    ((float4*)outp)[(size_t)node * 32 + lane] = acc;
}

// ================= fused edge MLP (MFMA bf16x3) =================
// z1 = relu(P[src] + Q[dst] + bm1)                        (built in registers as A-frags)
// z2 = relu(z1 @ Wm2 + bm2) via 16x16x32 bf16 MFMA, hi/lo split (3 MFMAs)
// out = sigmoid(z2 @ Wm3 + bm3)
__global__ __launch_bounds__(256) void k_edge_mlp_mfma(
    const int* __restrict__ esrc, const int* __restrict__ edst,
    const float* __restrict__ P, const float* __restrict__ Q,
    const float* __restrict__ bm1,
    const unsigned short* __restrict__ Whf, const unsigned short* __restrict__ Wlf,
    const float* __restrict__ bm2,
    const float* __restrict__ Wm3, const float* __restrict__ bm3,
    float* __restrict__ outp)
{
    __shared__ __align__(16) unsigned short sWh[16384];   // 32 KB, fragment layout
    __shared__ __align__(16) unsigned short sWl[16384];   // 32 KB
    __shared__ int sIdx[2][64];

    const int t = threadIdx.x;
    const int e0 = blockIdx.x * 64;

    // linear stage of pre-swizzled W fragments (2048 float4 each)
    #pragma unroll
    for (int i = 0; i < 8; ++i) {
        ((float4*)sWh)[t + 256 * i] = ((const float4*)Whf)[t + 256 * i];
        ((float4*)sWl)[t + 256 * i] = ((const float4*)Wlf)[t + 256 * i];
    }
    if (t < 64) sIdx[0][t] = esrc[e0 + t];
    else if (t < 128) sIdx[1][t - 64] = edst[e0 + t - 64];
    __syncthreads();

    const int w = t >> 6;          // wave id: rows w*16 .. w*16+15
    const int l = t & 63;
    const int lr = l & 15;         // A row within tile / D col
    const int lk = l >> 4;         // k-block
    const int row = w * 16 + lr;
    const int s = sIdx[0][row], d = sIdx[1][row];
    const float* prow = P + (size_t)s * 128 + lk * 8;
    const float* qrow = Q + (size_t)d * 128 + lk * 8;
    const float* brow = bm1 + lk * 8;

    // build A-fragments (z1 hi/lo) in registers
    bf16x8 ah[4], al[4];
    #pragma unroll
    for (int ks = 0; ks < 4; ++ks) {
        float4 p0 = *(const float4*)(prow + ks * 32);
        float4 p1 = *(const float4*)(prow + ks * 32 + 4);
        float4 q0 = *(const float4*)(qrow + ks * 32);
        float4 q1 = *(const float4*)(qrow + ks * 32 + 4);
        float4 b0 = *(const float4*)(brow + ks * 32);
        float4 b1 = *(const float4*)(brow + ks * 32 + 4);
        float z[8];
        z[0] = fmaxf(p0.x + q0.x + b0.x, 0.f);
        z[1] = fmaxf(p0.y + q0.y + b0.y, 0.f);
        z[2] = fmaxf(p0.z + q0.z + b0.z, 0.f);
        z[3] = fmaxf(p0.w + q0.w + b0.w, 0.f);
        z[4] = fmaxf(p1.x + q1.x + b1.x, 0.f);
        z[5] = fmaxf(p1.y + q1.y + b1.y, 0.f);
        z[6] = fmaxf(p1.z + q1.z + b1.z, 0.f);
        z[7] = fmaxf(p1.w + q1.w + b1.w, 0.f);
        #pragma unroll
        for (int e = 0; e < 8; ++e) {
            unsigned short hu = bf16_of(z[e]);
            ah[ks][e] = (short)hu;
            al[ks][e] = (short)bf16_of(z[e] - f32_of(hu));
        }
    }

    // C = z1 @ Wm2 + bm2  (8 col tiles of 16)
    f32x4 acc[8];
    #pragma unroll
    for (int ct = 0; ct < 8; ++ct) {
        float bv = bm2[ct * 16 + lr];
        f32x4 a = {bv, bv, bv, bv};
        acc[ct] = a;
    }

    #pragma unroll
    for (int ct = 0; ct < 8; ++ct) {
        #pragma unroll
        for (int ks = 0; ks < 4; ++ks) {
            const bf16x8 bh = *(const bf16x8*)(sWh + ((ks * 8 + ct) * 64 + l) * 8);
            const bf16x8 bl = *(const bf16x8*)(sWl + ((ks * 8 + ct) * 64 + l) * 8);
            acc[ct] = __builtin_amdgcn_mfma_f32_16x16x32_bf16(ah[ks], bh, acc[ct], 0, 0, 0);
            acc[ct] = __builtin_amdgcn_mfma_f32_16x16x32_bf16(ah[ks], bl, acc[ct], 0, 0, 0);
            acc[ct] = __builtin_amdgcn_mfma_f32_16x16x32_bf16(al[ks], bh, acc[ct], 0, 0, 0);
        }
    }

    // out = sigmoid(relu(C) @ Wm3 + bm3)
    // D layout: col = lr, row = lk*4 + reg
    float w3v[8];
    #pragma unroll
    for (int ct = 0; ct < 8; ++ct) w3v[ct] = Wm3[ct * 16 + lr];
    float b3 = bm3[0];
    #pragma unroll
    for (int j = 0; j < 4; ++j) {
        float pj = 0.f;
        #pragma unroll
        for (int ct = 0; ct < 8; ++ct) pj += fmaxf(acc[ct][j], 0.f) * w3v[ct];
        pj += __shfl_xor(pj, 1);
        pj += __shfl_xor(pj, 2);
        pj += __shfl_xor(pj, 4);
        pj += __shfl_xor(pj, 8);
        if (lr == 0)
            outp[e0 + w * 16 + lk * 4 + j] = 1.f / (1.f + expf(-(pj + b3)));
    }
}

// ================= launch =================
extern "C" void kernel_launch(void* const* d_in, const int* in_sizes, int n_in,
                              void* d_out, int out_size, void* d_ws, size_t ws_size,
                              hipStream_t stream) {
    const float* x   = (const float*)d_in[0];
    const int*   ei  = (const int*)d_in[1];
    const float* W1  = (const float*)d_in[2];
    const float* b1  = (const float*)d_in[3];
    const float* W2  = (const float*)d_in[4];
    const float* b2  = (const float*)d_in[5];
    const float* Wm1 = (const float*)d_in[6];
    const float* bm1 = (const float*)d_in[7];
    const float* Wm2 = (const float*)d_in[8];
    const float* bm2 = (const float*)d_in[9];
    const float* Wm3 = (const float*)d_in[10];
    const float* bm3 = (const float*)d_in[11];
    const int* esrc = ei;
    const int* edst = ei + N_EDGES;
    float* outp = (float*)d_out;

    // workspace layout
    float* ws = (float*)d_ws;
    float* dinv = ws;                                   // 100096 floats
    float* A = ws + 100096;                             // N*128
    float* B = A + (size_t)N_NODES * 128;               // N*128
    int* deg     = (int*)(B + (size_t)N_NODES * 128);   // N
    int* off     = deg + N_NODES;                       // N+1
    int* cur     = off + N_NODES + 1;                   // N
    int* bsum    = cur + N_NODES;                       // 512
    int* csr_src = bsum + 512;                          // E
    float* csr_w = (float*)(csr_src + N_EDGES);         // E
    unsigned short* Whf = (unsigned short*)(csr_w + N_EDGES);  // 16384
    unsigned short* Wlf = Whf + 16384;                         // 16384

    const int nb = (N_NODES + 255) / 256;               // 391 scan blocks

    // ---- CSR build + W split ----
    k_zero_deg<<<nb, 256, 0, stream>>>(deg);
    k_hist<<<(N_EDGES + 255) / 256, 256, 0, stream>>>(edst, deg);
    k_dinv<<<nb, 256, 0, stream>>>(deg, dinv);
    k_scan1<<<nb, 256, 0, stream>>>(deg, off, bsum, N_NODES);
    k_scan2<<<1, 512, 0, stream>>>(bsum, nb);
    k_scan3<<<(N_NODES + 256) / 256, 256, 0, stream>>>(off, bsum, cur, N_NODES);
    k_scatter<<<(N_EDGES + 255) / 256, 256, 0, stream>>>(esrc, edst, dinv, cur, csr_src, csr_w);
    k_split_w<<<64, 256, 0, stream>>>(Wm2, Whf, Wlf);

    const int gemm_blocks = (N_NODES + 63) / 64;
    const int agg_blocks = (N_NODES + 7) / 8;

    // ---- layer 1: A = x @ W1 ; B = b1 + norm-agg(A) ----
    k_node_gemm<false><<<gemm_blocks, 256, 0, stream>>>(x, W1, A, N_NODES);
    k_agg_csr<<<agg_blocks, 256, 0, stream>>>(A, dinv, off, csr_src, csr_w, b1, B);

    // ---- layer 2: A = relu(B) @ W2 ; B = b2 + norm-agg(A) ----
    k_node_gemm<true><<<gemm_blocks, 256, 0, stream>>>(B, W2, A, N_NODES);
    k_agg_csr<<<agg_blocks, 256, 0, stream>>>(A, dinv, off, csr_src, csr_w, b2, B);

    // ---- edge-MLP layer-1 decomposition (fused): P -> A, Q -> B (in-place safe) ----
    k_node_gemm_pq<<<gemm_blocks, 256, 0, stream>>>(B, Wm1, A, B, N_NODES);

    // ---- fused edge MLP on MFMA ----
    k_edge_mlp_mfma<<<N_EDGES / 64, 256, 0, stream>>>(esrc, edst, A, B, bm1,
                                                      Whf, Wlf, bm2, Wm3, bm3, outp);
}